// Round 2
// baseline (403.948 us; speedup 1.0000x reference)
//
#include <hip/hip_runtime.h>

// Elman RNN: h_{t+1} = tanh(x_t @ W_ih^T + b_ih + h @ W_hh^T + b_hh), T=512
// out = sigmoid(h_T @ fc_w^T + fc_b)
// One wave per sample; lane = hidden unit; weights in VGPRs as fp16 pairs;
// broadcasts via v_readlane; MACs via v_dot2_f32_f16 (fp32 accumulate).

#define RN 2048
#define RT 512
#define RI 32
#define RH 64

typedef _Float16 half2_t __attribute__((ext_vector_type(2)));

// cvt_pkrtz returns __fp16x2; bit_cast to the _Float16x2 fdot2 wants.
__device__ __forceinline__ half2_t pkrtz(float a, float b) {
    return __builtin_bit_cast(half2_t, __builtin_amdgcn_cvt_pkrtz(a, b));
}

__device__ __forceinline__ half2_t rl_h2(half2_t v, int lane) {
    int i = __builtin_bit_cast(int, v);
    int r = __builtin_amdgcn_readlane(i, lane);
    return __builtin_bit_cast(half2_t, r);
}

__global__ __launch_bounds__(256, 2) void rnn_fused(
    const float* __restrict__ x,
    const float* __restrict__ W_ih,
    const float* __restrict__ W_hh,
    const float* __restrict__ b_ih,
    const float* __restrict__ b_hh,
    const float* __restrict__ fc_w,
    const float* __restrict__ fc_b,
    float* __restrict__ out)
{
    const int lane = threadIdx.x & 63;
    const int wv   = threadIdx.x >> 6;
    const int n    = blockIdx.x * 4 + wv;

    // ---- preload weights (row `lane`) as fp16 pairs in VGPRs ----
    half2_t wih[RI / 2];
#pragma unroll
    for (int p = 0; p < RI / 2; ++p)
        wih[p] = pkrtz(W_ih[lane * RI + 2 * p], W_ih[lane * RI + 2 * p + 1]);
    half2_t whh[RH / 2];
#pragma unroll
    for (int q = 0; q < RH / 2; ++q)
        whh[q] = pkrtz(W_hh[lane * RH + 2 * q], W_hh[lane * RH + 2 * q + 1]);
    const float bias = b_ih[lane] + b_hh[lane];

    float   h   = 1.0f;                 // h0 = ones
    half2_t hpk = pkrtz(1.0f, 1.0f);    // (h[2*lane], h[2*lane+1])

    // x for this sample: [T][I] contiguous. 8 steps = 256 floats = 64 lanes x float4.
    const float4* xp = (const float4*)(x + (size_t)n * (RT * RI));
    float4 xr = xp[lane]; // t8 = 0 prefetched

    for (int t8 = 0; t8 < RT / 8; ++t8) {
        const int nxt = (t8 < RT / 8 - 1) ? (t8 + 1) : t8;
        float4 xr_next = xp[nxt * 64 + lane];

        // lane holds flat-pairs 2*lane (xr.x,xr.y) and 2*lane+1 (xr.z,xr.w)
        half2_t xpk0 = pkrtz(xr.x, xr.y);
        half2_t xpk1 = pkrtz(xr.z, xr.w);

#pragma unroll
        for (int dt = 0; dt < 8; ++dt) {
            float acc[4] = {bias, 0.f, 0.f, 0.f};

            // x_t @ W_ih^T : 16 fp16-pair dot2s
#pragma unroll
            for (int p = 0; p < RI / 2; ++p) {
                // flat pair P = dt*16 + p lives in lane P>>1 = dt*8 + (p>>1),
                // register parity = p&1
                half2_t xv = rl_h2((p & 1) ? xpk1 : xpk0, dt * 8 + (p >> 1));
                acc[p & 3] = __builtin_amdgcn_fdot2(xv, wih[p], acc[p & 3], false);
            }
            // h @ W_hh^T : 32 fp16-pair dot2s
#pragma unroll
            for (int q = 0; q < RH / 2; ++q) {
                half2_t hv = rl_h2(hpk, q);
                acc[q & 3] = __builtin_amdgcn_fdot2(hv, whh[q], acc[q & 3], false);
            }
            float z = (acc[0] + acc[1]) + (acc[2] + acc[3]);

            // fast tanh: 1 - 2/(e^{2z}+1); saturates correctly at +/-inf
            float e = __expf(2.0f * z);
            h = 1.0f - __fdividef(2.0f, e + 1.0f);

            // repack broadcast register: lane j holds (h[2j], h[2j+1]) (j<32 used)
            float hA = __shfl(h, 2 * lane);
            float hB = __shfl(h, 2 * lane + 1);
            hpk = pkrtz(hA, hB);
        }
        xr = xr_next;
    }

    // ---- epilogue: sigmoid(h . fc_w + fc_b) ----
    float z = h * fc_w[lane];
#pragma unroll
    for (int off = 32; off > 0; off >>= 1)
        z += __shfl_down(z, off);
    if (lane == 0) {
        float logit = z + fc_b[0];
        out[n] = __fdividef(1.0f, 1.0f + __expf(-logit));
    }
}

extern "C" void kernel_launch(void* const* d_in, const int* in_sizes, int n_in,
                              void* d_out, int out_size, void* d_ws, size_t ws_size,
                              hipStream_t stream) {
    rnn_fused<<<RN / 4, 256, 0, stream>>>(
        (const float*)d_in[0], (const float*)d_in[1], (const float*)d_in[2],
        (const float*)d_in[3], (const float*)d_in[4], (const float*)d_in[5],
        (const float*)d_in[6], (float*)d_out);
}